// Round 7
// baseline (279.582 us; speedup 1.0000x reference)
//
#include <hip/hip_runtime.h>

// ---------------------------------------------------------------------------
// GraphConvpoolMPNN fused rewrite. bs=16,S=17,N=256,F=64,MW=2 -> 256 windows,
// N1=512. One workgroup per window; nf slab (512x64 bf16) + xbT/out1T slab
// (64x512 bf16) resident in LDS (XOR-swizzled). adj2@xb == adj@(adj@xb).
// R7: amdgpu_waves_per_eu(2,2) on k_mega. R5/R6 showed VGPR_Count pinned at
// 128 (compiler's default occupancy target; it cannot see the 142 KB dynamic
// LDS that already caps the CU at 1 WG = 2 waves/EU), causing ~200 MB of
// scratch spill per dispatch (FETCH 88 / WRITE 153 MB vs ~17/17 algorithmic).
// Pinning waves/EU=2 raises the register budget to 512/2 = 256 VGPRs, which
// holds the ~210-reg live set without spill.
// Pipeline: k_prep (detect+canon+zero) -> k_y (x@W^T + BN0 stats)
//           -> k_mega (scores/softmax/mask/2 hops/projection + BN1 stats)
//           -> k_final (BN1 + lrelu + window mean) -> fp32 out.
// ---------------------------------------------------------------------------

typedef unsigned short u16;
typedef __bf16 bf16x8 __attribute__((ext_vector_type(8)));
typedef float f32x4 __attribute__((ext_vector_type(4)));
typedef unsigned int u32x4 __attribute__((ext_vector_type(4)));

#define MFMA16(a, b, c) __builtin_amdgcn_mfma_f32_16x16x32_bf16(a, b, c, 0, 0, 0)

#define BSZ 16
#define SNUM 17
#define FD 64
#define NB 256
#define N1 512
#define SL_ELEMS 16384
#define Y_ELEMS (BSZ * SNUM * SL_ELEMS)

// canonical param buffer offsets (u16 elements)
#define WM_O 0
#define BM_O 4096
#define B0W_O 4160
#define B0B_O 4224
#define T0W_O 4288
#define T0B_O 8384
#define T1W_O 8448
#define T1B_O 12544
#define B1W_O 12608
#define B1B_O 12672
#define P_TOT 12736

// k_mega LDS map (u16 units): slab1 [512][64] XOR, slab2 [64][512] XOR,
// red 128 floats, scr 8 waves x (16 rows x 40)
#define SLAB2_O 32768
#define RED_O 65536
#define SCR_O 65792
#define LDS_BYTES ((SCR_O + 8 * 640) * 2)  // 141,824 B -> 1 WG/CU

__device__ __forceinline__ float bf2f(u16 u) {
    union { unsigned int i; float f; } v;
    v.i = ((unsigned int)u) << 16;
    return v.f;
}
__device__ __forceinline__ u16 f2bu(float f) {  // RNE via HW cvt
    __bf16 h = (__bf16)f;
    return __builtin_bit_cast(u16, h);
}
__device__ __forceinline__ u16 f2bf(float f) {  // manual RNE (canon path)
    unsigned int u = __builtin_bit_cast(unsigned int, f);
    unsigned int r = (u + 0x7fffu + ((u >> 16) & 1u)) >> 16;
    return (u16)r;
}
__device__ __forceinline__ bf16x8 ld8g(const u16* p) {
    return __builtin_bit_cast(bf16x8, *reinterpret_cast<const u32x4*>(p));
}

// ---------------- prep: dtype detect + canon params + zero stats -----------
__global__ __launch_bounds__(256) void k_prep(
    const void* p0, const void* p1, const void* p2, const void* p3,
    const void* p4, const void* p5, const void* p6, const void* p7,
    const void* p8, const void* p9, int* __restrict__ flagOut,
    u16* __restrict__ pc, float* __restrict__ stats) {
    const int tid = threadIdx.x, lane = tid & 63;
    int z = 0, bc = 0;
    const unsigned int* w = (const unsigned int*)p0;
    for (int i = lane; i < 2048; i += 64) {
        const unsigned int v = w[i];
        z += ((v & 0xffffu) == 0u);
        bc += (v >> 14) & 1;
    }
#pragma unroll
    for (int o = 1; o < 64; o <<= 1) {
        z += __shfl_xor(z, o);
        bc += __shfl_xor(bc, o);
    }
    const int flag = (z > 1024 || bc > 256) ? 1 : 0;
    if (blockIdx.x == 0) {
        if (tid == 0) *flagOut = flag;
        if (tid < 256) stats[tid] = 0.f;
    }
    const int i = blockIdx.x * 256 + tid;
    if (i >= P_TOT) return;
    const void* src;
    int si;
    if (i < BM_O)        { src = p0; si = i; }
    else if (i < B0W_O)  { src = p1; si = i - BM_O; }
    else if (i < B0B_O)  { src = p2; si = i - B0W_O; }
    else if (i < T0W_O)  { src = p3; si = i - B0B_O; }
    else if (i < T0B_O)  { src = p4; si = i - T0W_O; }
    else if (i < T1W_O)  { src = p5; si = i - T0B_O; }
    else if (i < T1B_O)  { src = p6; si = i - T1W_O; }
    else if (i < B1W_O)  { src = p7; si = i - T1B_O; }
    else if (i < B1B_O)  { src = p8; si = i - B1W_O; }
    else                 { src = p9; si = i - B1B_O; }
    pc[i] = flag ? f2bf(((const float*)src)[si]) : ((const u16*)src)[si];
}

// ------------------- y = x @ W^T + b  (+ fused BN0 stats) ------------------
__global__ __launch_bounds__(256) void k_y(const void* __restrict__ xv,
                                           const int* __restrict__ flag,
                                           const u16* __restrict__ pc,
                                           u16* __restrict__ y,
                                           float* __restrict__ gstats) {
    const int slice = blockIdx.x;  // 272
    const int tid = threadIdx.x, wave = tid >> 6, lane = tid & 63;
    const int quad = lane >> 4, l16 = lane & 15;
    __shared__ float red[128];
    if (tid < 128) red[tid] = 0.f;
    const int isf32 = *flag;

    f32x4 acc[4][4];
#pragma unroll
    for (int i = 0; i < 4; i++)
#pragma unroll
        for (int j = 0; j < 4; j++) acc[i][j] = (f32x4){0.f, 0.f, 0.f, 0.f};

    bf16x8 bfr[4][2];
#pragma unroll
    for (int nt = 0; nt < 4; nt++)
#pragma unroll
        for (int kh = 0; kh < 2; kh++)
            bfr[nt][kh] = ld8g(pc + WM_O + (nt * 16 + l16) * 64 + kh * 32 + quad * 8);

    const float* xf = (const float*)xv + (size_t)slice * SL_ELEMS;
    const u16* xh = (const u16*)xv + (size_t)slice * SL_ELEMS;

#pragma unroll
    for (int mt = 0; mt < 4; mt++) {
        const int row = wave * 64 + mt * 16 + l16;
        bf16x8 a0, a1;
        if (isf32) {
            const float* r0 = xf + row * 64 + quad * 8;
            f32x4 v0 = *(const f32x4*)r0;
            f32x4 v1 = *(const f32x4*)(r0 + 4);
            f32x4 v2 = *(const f32x4*)(r0 + 32);
            f32x4 v3 = *(const f32x4*)(r0 + 36);
#pragma unroll
            for (int j = 0; j < 4; j++) {
                a0[j] = (__bf16)v0[j]; a0[4 + j] = (__bf16)v1[j];
                a1[j] = (__bf16)v2[j]; a1[4 + j] = (__bf16)v3[j];
            }
        } else {
            a0 = ld8g(xh + row * 64 + quad * 8);
            a1 = ld8g(xh + row * 64 + 32 + quad * 8);
        }
#pragma unroll
        for (int nt = 0; nt < 4; nt++)
            acc[mt][nt] = MFMA16(a1, bfr[nt][1], MFMA16(a0, bfr[nt][0], acc[mt][nt]));
    }

    u16* ys = y + (size_t)slice * SL_ELEMS;
    float s1[4] = {0.f, 0.f, 0.f, 0.f}, s2[4] = {0.f, 0.f, 0.f, 0.f};
#pragma unroll
    for (int nt = 0; nt < 4; nt++) {
        const int col = nt * 16 + l16;
        const float bias = bf2f(pc[BM_O + col]);
#pragma unroll
        for (int mt = 0; mt < 4; mt++)
#pragma unroll
            for (int r = 0; r < 4; r++) {
                const int row = wave * 64 + mt * 16 + quad * 4 + r;
                const float v = acc[mt][nt][r] + bias;
                ys[row * 64 + col] = f2bu(v);
                s1[nt] += v;
                s2[nt] += v * v;
            }
        s1[nt] += __shfl_xor(s1[nt], 16); s1[nt] += __shfl_xor(s1[nt], 32);
        s2[nt] += __shfl_xor(s2[nt], 16); s2[nt] += __shfl_xor(s2[nt], 32);
    }
    __syncthreads();
    if (quad == 0) {
#pragma unroll
        for (int nt = 0; nt < 4; nt++) {
            atomicAdd(&red[nt * 16 + l16], s1[nt]);
            atomicAdd(&red[64 + nt * 16 + l16], s2[nt]);
        }
    }
    __syncthreads();
    const int s = slice % SNUM;
    const float wgt = (s == 0 || s == SNUM - 1) ? 1.f : 2.f;
    if (tid < 128) atomicAdd(&gstats[tid], red[tid] * wgt);
}

// --------------------------- the fused window kernel -----------------------
// waves_per_eu(2,2): 512 threads = 8 waves = exactly 2 waves/EU (the floor
// for one co-resident WG; 142 KB dynamic LDS caps the CU at 1 WG anyway).
// This raises the VGPR budget to 512/2 = 256, fitting the ~210-reg live set.
__global__ __launch_bounds__(512)
__attribute__((amdgpu_waves_per_eu(2, 2))) void k_mega(
    const u16* __restrict__ y, float* __restrict__ stats,
    const u16* __restrict__ pc, u16* __restrict__ opre) {
    extern __shared__ u16 lds[];
    u16* slab1 = lds;                       // [n 0..511][g 0..7] XOR(n&7)
    u16* slab2 = lds + SLAB2_O;             // [f 0..63][gn 0..63] XOR(f)
    float* red = (float*)(lds + RED_O);     // 128 floats for BN1 partials
    const int tid = threadIdx.x, w = tid >> 6, lane = tid & 63;
    const int quad = lane >> 4, l16 = lane & 15;
    u16* scr = lds + SCR_O + w * 640;       // 16 rows x 40 u16, per wave
    const int p = blockIdx.x, b = p >> 4, l = p & 15;
    const f32x4 ZERO4 = (f32x4){0.f, 0.f, 0.f, 0.f};

    if (tid < 128) red[tid] = 0.f;

    // BN0 affine constants
    const float cinv = 1.f / 131072.f;
    const int fme = tid & 63;
    float mu0 = stats[fme] * cinv;
    float vr0 = fmaxf(stats[64 + fme] * cinv - mu0 * mu0, 0.f);
    const float scale_f = rsqrtf(vr0 + 1e-5f) * bf2f(pc[B0W_O + fme]);
    const float shift_f = bf2f(pc[B0B_O + fme]) - mu0 * scale_f;
    float escl[4], eshf[4];
#pragma unroll
    for (int ft = 0; ft < 4; ft++) {
        const int col = ft * 16 + l16;
        float m = stats[col] * cinv;
        float v = fmaxf(stats[64 + col] * cinv - m * m, 0.f);
        escl[ft] = rsqrtf(v + 1e-5f) * bf2f(pc[B0W_O + col]);
        eshf[ft] = bf2f(pc[B0B_O + col]) - m * escl[ft];
    }

    // stage nf slab (two consecutive slices = contiguous 512x64)
    const u16* ybase = y + (size_t)(b * SNUM + l) * SL_ELEMS;
#pragma unroll
    for (int i = 0; i < 8; i++) {
        const int gid = i * 512 + tid, n = gid >> 3, g = gid & 7;
        *(u32x4*)(slab1 + n * 64 + ((g ^ (n & 7)) << 3)) =
            *(const u32x4*)(ybase + n * 64 + g * 8);
    }
    __syncthreads();

    // build slab2 = xbT = BN0(nf) transposed, bf16
#pragma unroll
    for (int i = 0; i < 8; i++) {
        const int gn = (tid >> 6) + i * 8;
        union { u16 u[8]; u32x4 v; } pk;
#pragma unroll
        for (int j = 0; j < 8; j++) {
            const int n = gn * 8 + j;
            const u16 raw = slab1[n * 64 + (((fme >> 3) ^ (n & 7)) << 3) + (fme & 7)];
            pk.u[j] = f2bu(bf2f(raw) * scale_f + shift_f);
        }
        *(u32x4*)(slab2 + fme * 512 + ((gn ^ fme) << 3)) = pk.v;
    }
    __syncthreads();

    // hoist nf A-frags for this wave's 64 rows (4 subtiles of 16)
    bf16x8 a[4][2];
#pragma unroll
    for (int st = 0; st < 4; st++)
#pragma unroll
        for (int h = 0; h < 2; h++) {
            const int row = w * 64 + st * 16 + l16;
            a[st][h] = *(const bf16x8*)(slab1 + row * 64 + (((h * 4 + quad) ^ (row & 7)) << 3));
        }

    for (int pass = 0; pass < 2; pass++) {
        f32x4 oacc[4][4];
        f32x4 lsum[4];
#pragma unroll
        for (int st = 0; st < 4; st++) {
            lsum[st] = ZERO4;
#pragma unroll
            for (int ft = 0; ft < 4; ft++) oacc[st][ft] = ZERO4;
        }

        for (int c = 0; c < 8; c++) {
            const float mf = ((w >= 4) == (c >= 4)) ? 1.f : 0.7f;
            bf16x8 bs[4][2], bv[2][4];
#pragma unroll
            for (int jt = 0; jt < 4; jt++)
#pragma unroll
                for (int h = 0; h < 2; h++) {
                    const int rj = c * 64 + jt * 16 + l16;
                    bs[jt][h] = *(const bf16x8*)(slab1 + rj * 64 + (((h * 4 + quad) ^ (rj & 7)) << 3));
                }
#pragma unroll
            for (int h = 0; h < 2; h++)
#pragma unroll
                for (int ft = 0; ft < 4; ft++) {
                    const int f = ft * 16 + l16, gn = c * 8 + h * 4 + quad;
                    bv[h][ft] = *(const bf16x8*)(slab2 + f * 512 + ((gn ^ f) << 3));
                }
#pragma unroll
            for (int st = 0; st < 4; st++) {
                f32x4 S[4];
#pragma unroll
                for (int jt = 0; jt < 4; jt++) {
                    f32x4 t = MFMA16(a[st][0], bs[jt][0], ZERO4);
                    S[jt] = MFMA16(a[st][1], bs[jt][1], t);
                }
                u16 pb[4][4];
#pragma unroll
                for (int jt = 0; jt < 4; jt++)
#pragma unroll
                    for (int r = 0; r < 4; r++) {
                        const float s = S[jt][r];
                        // leaky_relu folded into exp2 domain
                        const float m2 = s > 0.f ? 1.44269504f : 0.0144269504f;
                        float pv = exp2f(fminf(s * m2, 86.f));
                        if (jt == st && c == w && l16 == quad * 4 + r) pv = 0.f;  // diag
                        lsum[st][r] += pv;
                        pb[jt][r] = f2bu(pv * mf);
                    }
#pragma unroll
                for (int h = 0; h < 2; h++) {
#pragma unroll
                    for (int jtl = 0; jtl < 2; jtl++)
#pragma unroll
                        for (int r = 0; r < 4; r++)
                            scr[(quad * 4 + r) * 40 + jtl * 16 + l16] = pb[2 * h + jtl][r];
                    const bf16x8 pa = *(const bf16x8*)(scr + l16 * 40 + quad * 8);
#pragma unroll
                    for (int ft = 0; ft < 4; ft++)
                        oacc[st][ft] = MFMA16(pa, bv[h][ft], oacc[st][ft]);
                }
            }
        }
        // softmax denominators (per row, butterfly over the 16 col-lanes)
#pragma unroll
        for (int st = 0; st < 4; st++)
#pragma unroll
            for (int r = 0; r < 4; r++) {
                lsum[st][r] += __shfl_xor(lsum[st][r], 1);
                lsum[st][r] += __shfl_xor(lsum[st][r], 2);
                lsum[st][r] += __shfl_xor(lsum[st][r], 4);
                lsum[st][r] += __shfl_xor(lsum[st][r], 8);
            }

        if (pass == 0) {
            // out1 = P@xb / l + xb(own row)
#pragma unroll
            for (int st = 0; st < 4; st++) {
                f32x4 inv;
#pragma unroll
                for (int r = 0; r < 4; r++) inv[r] = __builtin_amdgcn_rcpf(lsum[st][r]);
#pragma unroll
                for (int ft = 0; ft < 4; ft++)
#pragma unroll
                    for (int r = 0; r < 4; r++) {
                        const int i = w * 64 + st * 16 + quad * 4 + r;
                        const int col = ft * 16 + l16;
                        const float xbv =
                            bf2f(slab1[i * 64 + (((col >> 3) ^ (i & 7)) << 3) + (col & 7)]) * escl[ft] + eshf[ft];
                        oacc[st][ft][r] = oacc[st][ft][r] * inv[r] + xbv;
                    }
            }
            __syncthreads();  // all waves done reading xbT
#pragma unroll
            for (int st = 0; st < 4; st++)
#pragma unroll
                for (int ft = 0; ft < 4; ft++)
#pragma unroll
                    for (int r = 0; r < 4; r++) {
                        const int i = w * 64 + st * 16 + quad * 4 + r;
                        const int f = ft * 16 + l16;
                        slab2[f * 512 + (((i >> 3) ^ f) << 3) + (i & 7)] = f2bu(oacc[st][ft][r]);
                    }
            __syncthreads();  // out1T visible for pass 1
        } else {
            // out2 = P@out1 / l + out1(own); fused projection + BN1 partials
            float s1a[4] = {0.f, 0.f, 0.f, 0.f}, s2a[4] = {0.f, 0.f, 0.f, 0.f};
            bf16x8 w0f[2][4], w1f[2][4];
#pragma unroll
            for (int h = 0; h < 2; h++)
#pragma unroll
                for (int ot = 0; ot < 4; ot++) {
                    const int o = ot * 16 + l16;
                    w0f[h][ot] = ld8g(pc + T0W_O + o * 64 + h * 32 + quad * 8);
                    w1f[h][ot] = ld8g(pc + T1W_O + o * 64 + h * 32 + quad * 8);
                }
#pragma unroll
            for (int st = 0; st < 4; st++) {
                f32x4 inv;
#pragma unroll
                for (int r = 0; r < 4; r++) inv[r] = __builtin_amdgcn_rcpf(lsum[st][r]);
#pragma unroll
                for (int ft = 0; ft < 4; ft++)
#pragma unroll
                    for (int r = 0; r < 4; r++) {
                        const int i = w * 64 + st * 16 + quad * 4 + r;
                        const int col = ft * 16 + l16;
                        const float o1 = bf2f(slab2[col * 512 + (((i >> 3) ^ col) << 3) + (i & 7)]);
                        oacc[st][ft][r] = oacc[st][ft][r] * inv[r] + o1;
                    }
                // a1 = out1 A-frag (from out1T slab, scalar gather)
                bf16x8 a1[2], a2[2];
                const int irow = w * 64 + st * 16 + l16;
#pragma unroll
                for (int h = 0; h < 2; h++)
#pragma unroll
                    for (int j = 0; j < 8; j++) {
                        const int f = h * 32 + quad * 8 + j;
                        const u16 raw = slab2[f * 512 + (((irow >> 3) ^ f) << 3) + (irow & 7)];
                        a1[h][j] = __builtin_bit_cast(__bf16, raw);
                    }
                // a2 = out2 A-frag via per-wave scratch
#pragma unroll
                for (int h = 0; h < 2; h++) {
#pragma unroll
                    for (int ftl = 0; ftl < 2; ftl++)
#pragma unroll
                        for (int r = 0; r < 4; r++)
                            scr[(quad * 4 + r) * 40 + ftl * 16 + l16] = f2bu(oacc[st][2 * h + ftl][r]);
                    a2[h] = *(const bf16x8*)(scr + l16 * 40 + quad * 8);
                }
                f32x4 pacc[4];
#pragma unroll
                for (int ot = 0; ot < 4; ot++) {
                    const int o = ot * 16 + l16;
                    const float bias = bf2f(pc[T0B_O + o]) + bf2f(pc[T1B_O + o]);
                    pacc[ot] = (f32x4){bias, bias, bias, bias};
                }
#pragma unroll
                for (int h = 0; h < 2; h++)
#pragma unroll
                    for (int ot = 0; ot < 4; ot++) {
                        pacc[ot] = MFMA16(a1[h], w0f[h][ot], pacc[ot]);
                        pacc[ot] = MFMA16(a2[h], w1f[h][ot], pacc[ot]);
                    }
#pragma unroll
                for (int ot = 0; ot < 4; ot++)
#pragma unroll
                    for (int r = 0; r < 4; r++) {
                        const int i = w * 64 + st * 16 + quad * 4 + r;
                        const int o = ot * 16 + l16;
                        const float v = pacc[ot][r];
                        s1a[ot] += v;
                        s2a[ot] += v * v;
                        opre[(size_t)p * (N1 * FD) + (size_t)i * 64 + o] = f2bu(v);
                    }
            }
#pragma unroll
            for (int ot = 0; ot < 4; ot++) {
                s1a[ot] += __shfl_xor(s1a[ot], 16); s1a[ot] += __shfl_xor(s1a[ot], 32);
                s2a[ot] += __shfl_xor(s2a[ot], 16); s2a[ot] += __shfl_xor(s2a[ot], 32);
            }
            if (quad == 0) {
#pragma unroll
                for (int ot = 0; ot < 4; ot++) {
                    atomicAdd(&red[ot * 16 + l16], s1a[ot]);
                    atomicAdd(&red[64 + ot * 16 + l16], s2a[ot]);
                }
            }
            __syncthreads();
            if (tid < 128) atomicAdd(&stats[128 + tid], red[tid]);
        }
    }
}

// --------------------------- BN1 + lrelu + pooling -> fp32 out -------------
__global__ __launch_bounds__(256) void k_final(const u16* __restrict__ op,
                                               const float* __restrict__ stats,
                                               const u16* __restrict__ pc,
                                               float* __restrict__ out) {
    const int o = blockIdx.x * 256 + threadIdx.x;
    const int f = o & 63, n = (o >> 6) & 255, b = o >> 14;
    const float inv = 1.f / 131072.f;
    const float mu = stats[128 + f] * inv;
    const float var = fmaxf(stats[192 + f] * inv - mu * mu, 0.f);
    const float rs = rsqrtf(var + 1e-5f);
    const float scale = rs * bf2f(pc[B1W_O + f]);
    const float shift = bf2f(pc[B1B_O + f]) - mu * scale;
    float acc = 0.f;
    for (int l = 0; l < 16; l++) {
        const size_t pb = (size_t)(b * 16 + l) * N1 * FD;
#pragma unroll
        for (int m = 0; m < 2; m++) {
            float v = bf2f(op[pb + (size_t)(m * 256 + n) * 64 + f]);
            v = v * scale + shift;
            acc += (v > 0.f ? v : 0.01f * v);
        }
    }
    out[o] = acc * (1.f / 32.f);
}

// ---------------------------------------------------------------------------
extern "C" void kernel_launch(void* const* d_in, const int* in_sizes, int n_in,
                              void* d_out, int out_size, void* d_ws, size_t ws_size,
                              hipStream_t stream) {
    char* ws = (char*)d_ws;
    size_t off = 0;
    auto alloc = [&](size_t bytes) { void* pp = ws + off; off += (bytes + 255) & ~(size_t)255; return pp; };
    u16* y = (u16*)alloc((size_t)Y_ELEMS * 2);
    u16* opre = (u16*)alloc((size_t)NB * N1 * FD * 2);
    u16* pc = (u16*)alloc(P_TOT * 2);
    float* stats = (float*)alloc(256 * 4);
    int* flag = (int*)alloc(256);
    float* out = (float*)d_out;

    k_prep<<<50, 256, 0, stream>>>(d_in[1], d_in[2], d_in[3], d_in[4], d_in[5],
                                   d_in[6], d_in[7], d_in[8], d_in[9], d_in[10],
                                   flag, pc, stats);
    k_y<<<BSZ * SNUM, 256, 0, stream>>>(d_in[0], flag, pc, y, stats);
    k_mega<<<NB, 512, LDS_BYTES, stream>>>(y, stats, pc, opre);
    k_final<<<1024, 256, 0, stream>>>(opre, stats, pc, out);
}

// Round 8
// 203.695 us; speedup vs baseline: 1.3726x; 1.3726x over previous
//
#include <hip/hip_runtime.h>

// ---------------------------------------------------------------------------
// GraphConvpoolMPNN fused rewrite. bs=16,S=17,N=256,F=64,MW=2 -> 256 windows,
// N1=512. One workgroup per window; nf slab (512x64 bf16) + xbT/out1T slab
// (64x512 bf16) resident in LDS (XOR-swizzled). adj2@xb == adj@(adj@xb).
// R8: k_mega -> 1024 threads / 16 waves, 32 rows per wave, col-half split of
// each 64-col block. R5-R7 proved the 512-thread version's ~210-reg live set
// can't escape the 128-VGPR cap (waves_per_eu ignored; ~200 MB/dispatch of
// scratch spill: FETCH 88 / WRITE 153 MB vs ~17/17 algorithmic). Halving the
// per-wave tile (oacc 64->32, a 32->16) + halving per-iter temps (bs/bv/S)
// brings the peak to ~125 regs == the budget the compiler must use anyway
// for a 1024-thread WG. Occupancy doubles (16 waves/CU).
// Pipeline: k_prep (detect+canon+zero) -> k_y (x@W^T + BN0 stats)
//           -> k_mega (scores/softmax/mask/2 hops/projection + BN1 stats)
//           -> k_final (BN1 + lrelu + window mean) -> fp32 out.
// ---------------------------------------------------------------------------

typedef unsigned short u16;
typedef __bf16 bf16x8 __attribute__((ext_vector_type(8)));
typedef float f32x4 __attribute__((ext_vector_type(4)));
typedef unsigned int u32x4 __attribute__((ext_vector_type(4)));

#define MFMA16(a, b, c) __builtin_amdgcn_mfma_f32_16x16x32_bf16(a, b, c, 0, 0, 0)

#define BSZ 16
#define SNUM 17
#define FD 64
#define NB 256
#define N1 512
#define SL_ELEMS 16384
#define Y_ELEMS (BSZ * SNUM * SL_ELEMS)

// canonical param buffer offsets (u16 elements)
#define WM_O 0
#define BM_O 4096
#define B0W_O 4160
#define B0B_O 4224
#define T0W_O 4288
#define T0B_O 8384
#define T1W_O 8448
#define T1B_O 12544
#define B1W_O 12608
#define B1B_O 12672
#define P_TOT 12736

// k_mega LDS map (u16 units): slab1 [512][64] XOR, slab2 [64][512] XOR,
// red 128 floats (256 u16), scr 16 waves x (16 rows x 40)
#define SLAB2_O 32768
#define RED_O 65536
#define SCR_O 65792
#define LDS_BYTES ((SCR_O + 16 * 640) * 2)  // 152,064 B -> 1 WG/CU

__device__ __forceinline__ float bf2f(u16 u) {
    union { unsigned int i; float f; } v;
    v.i = ((unsigned int)u) << 16;
    return v.f;
}
__device__ __forceinline__ u16 f2bu(float f) {  // RNE via HW cvt
    __bf16 h = (__bf16)f;
    return __builtin_bit_cast(u16, h);
}
__device__ __forceinline__ u16 f2bf(float f) {  // manual RNE (canon path)
    unsigned int u = __builtin_bit_cast(unsigned int, f);
    unsigned int r = (u + 0x7fffu + ((u >> 16) & 1u)) >> 16;
    return (u16)r;
}
__device__ __forceinline__ bf16x8 ld8g(const u16* p) {
    return __builtin_bit_cast(bf16x8, *reinterpret_cast<const u32x4*>(p));
}

// ---------------- prep: dtype detect + canon params + zero stats -----------
__global__ __launch_bounds__(256) void k_prep(
    const void* p0, const void* p1, const void* p2, const void* p3,
    const void* p4, const void* p5, const void* p6, const void* p7,
    const void* p8, const void* p9, int* __restrict__ flagOut,
    u16* __restrict__ pc, float* __restrict__ stats) {
    const int tid = threadIdx.x, lane = tid & 63;
    int z = 0, bc = 0;
    const unsigned int* w = (const unsigned int*)p0;
    for (int i = lane; i < 2048; i += 64) {
        const unsigned int v = w[i];
        z += ((v & 0xffffu) == 0u);
        bc += (v >> 14) & 1;
    }
#pragma unroll
    for (int o = 1; o < 64; o <<= 1) {
        z += __shfl_xor(z, o);
        bc += __shfl_xor(bc, o);
    }
    const int flag = (z > 1024 || bc > 256) ? 1 : 0;
    if (blockIdx.x == 0) {
        if (tid == 0) *flagOut = flag;
        if (tid < 256) stats[tid] = 0.f;
    }
    const int i = blockIdx.x * 256 + tid;
    if (i >= P_TOT) return;
    const void* src;
    int si;
    if (i < BM_O)        { src = p0; si = i; }
    else if (i < B0W_O)  { src = p1; si = i - BM_O; }
    else if (i < B0B_O)  { src = p2; si = i - B0W_O; }
    else if (i < T0W_O)  { src = p3; si = i - B0B_O; }
    else if (i < T0B_O)  { src = p4; si = i - T0W_O; }
    else if (i < T1W_O)  { src = p5; si = i - T0B_O; }
    else if (i < T1B_O)  { src = p6; si = i - T1W_O; }
    else if (i < B1W_O)  { src = p7; si = i - T1B_O; }
    else if (i < B1B_O)  { src = p8; si = i - B1W_O; }
    else                 { src = p9; si = i - B1B_O; }
    pc[i] = flag ? f2bf(((const float*)src)[si]) : ((const u16*)src)[si];
}

// ------------------- y = x @ W^T + b  (+ fused BN0 stats) ------------------
__global__ __launch_bounds__(256) void k_y(const void* __restrict__ xv,
                                           const int* __restrict__ flag,
                                           const u16* __restrict__ pc,
                                           u16* __restrict__ y,
                                           float* __restrict__ gstats) {
    const int slice = blockIdx.x;  // 272
    const int tid = threadIdx.x, wave = tid >> 6, lane = tid & 63;
    const int quad = lane >> 4, l16 = lane & 15;
    __shared__ float red[128];
    if (tid < 128) red[tid] = 0.f;
    const int isf32 = *flag;

    f32x4 acc[4][4];
#pragma unroll
    for (int i = 0; i < 4; i++)
#pragma unroll
        for (int j = 0; j < 4; j++) acc[i][j] = (f32x4){0.f, 0.f, 0.f, 0.f};

    bf16x8 bfr[4][2];
#pragma unroll
    for (int nt = 0; nt < 4; nt++)
#pragma unroll
        for (int kh = 0; kh < 2; kh++)
            bfr[nt][kh] = ld8g(pc + WM_O + (nt * 16 + l16) * 64 + kh * 32 + quad * 8);

    const float* xf = (const float*)xv + (size_t)slice * SL_ELEMS;
    const u16* xh = (const u16*)xv + (size_t)slice * SL_ELEMS;

#pragma unroll
    for (int mt = 0; mt < 4; mt++) {
        const int row = wave * 64 + mt * 16 + l16;
        bf16x8 a0, a1;
        if (isf32) {
            const float* r0 = xf + row * 64 + quad * 8;
            f32x4 v0 = *(const f32x4*)r0;
            f32x4 v1 = *(const f32x4*)(r0 + 4);
            f32x4 v2 = *(const f32x4*)(r0 + 32);
            f32x4 v3 = *(const f32x4*)(r0 + 36);
#pragma unroll
            for (int j = 0; j < 4; j++) {
                a0[j] = (__bf16)v0[j]; a0[4 + j] = (__bf16)v1[j];
                a1[j] = (__bf16)v2[j]; a1[4 + j] = (__bf16)v3[j];
            }
        } else {
            a0 = ld8g(xh + row * 64 + quad * 8);
            a1 = ld8g(xh + row * 64 + 32 + quad * 8);
        }
#pragma unroll
        for (int nt = 0; nt < 4; nt++)
            acc[mt][nt] = MFMA16(a1, bfr[nt][1], MFMA16(a0, bfr[nt][0], acc[mt][nt]));
    }

    u16* ys = y + (size_t)slice * SL_ELEMS;
    float s1[4] = {0.f, 0.f, 0.f, 0.f}, s2[4] = {0.f, 0.f, 0.f, 0.f};
#pragma unroll
    for (int nt = 0; nt < 4; nt++) {
        const int col = nt * 16 + l16;
        const float bias = bf2f(pc[BM_O + col]);
#pragma unroll
        for (int mt = 0; mt < 4; mt++)
#pragma unroll
            for (int r = 0; r < 4; r++) {
                const int row = wave * 64 + mt * 16 + quad * 4 + r;
                const float v = acc[mt][nt][r] + bias;
                ys[row * 64 + col] = f2bu(v);
                s1[nt] += v;
                s2[nt] += v * v;
            }
        s1[nt] += __shfl_xor(s1[nt], 16); s1[nt] += __shfl_xor(s1[nt], 32);
        s2[nt] += __shfl_xor(s2[nt], 16); s2[nt] += __shfl_xor(s2[nt], 32);
    }
    __syncthreads();
    if (quad == 0) {
#pragma unroll
        for (int nt = 0; nt < 4; nt++) {
            atomicAdd(&red[nt * 16 + l16], s1[nt]);
            atomicAdd(&red[64 + nt * 16 + l16], s2[nt]);
        }
    }
    __syncthreads();
    const int s = slice % SNUM;
    const float wgt = (s == 0 || s == SNUM - 1) ? 1.f : 2.f;
    if (tid < 128) atomicAdd(&gstats[tid], red[tid] * wgt);
}

// --------------------------- the fused window kernel -----------------------
// 1024 threads / 16 waves; each wave owns 32 rows (2 subtiles of 16).
__global__ __launch_bounds__(1024) void k_mega(
    const u16* __restrict__ y, float* __restrict__ stats,
    const u16* __restrict__ pc, u16* __restrict__ opre) {
    extern __shared__ u16 lds[];
    u16* slab1 = lds;                       // [n 0..511][g 0..7] XOR(n&7)
    u16* slab2 = lds + SLAB2_O;             // [f 0..63][gn 0..63] XOR(f)
    float* red = (float*)(lds + RED_O);     // 128 floats for BN1 partials
    const int tid = threadIdx.x, w = tid >> 6, lane = tid & 63;
    const int quad = lane >> 4, l16 = lane & 15;
    u16* scr = lds + SCR_O + w * 640;       // 16 rows x 40 u16, per wave
    const int p = blockIdx.x, b = p >> 4, l = p & 15;
    const f32x4 ZERO4 = (f32x4){0.f, 0.f, 0.f, 0.f};

    if (tid < 128) red[tid] = 0.f;

    // BN0 affine constants (only for slab2 build; per thread channel fme)
    const float cinv = 1.f / 131072.f;
    const int fme = tid & 63;
    float mu0 = stats[fme] * cinv;
    float vr0 = fmaxf(stats[64 + fme] * cinv - mu0 * mu0, 0.f);
    const float scale_f = rsqrtf(vr0 + 1e-5f) * bf2f(pc[B0W_O + fme]);
    const float shift_f = bf2f(pc[B0B_O + fme]) - mu0 * scale_f;

    // stage nf slab (two consecutive slices = contiguous 512x64)
    const u16* ybase = y + (size_t)(b * SNUM + l) * SL_ELEMS;
#pragma unroll
    for (int i = 0; i < 4; i++) {
        const int gid = i * 1024 + tid, n = gid >> 3, g = gid & 7;
        *(u32x4*)(slab1 + n * 64 + ((g ^ (n & 7)) << 3)) =
            *(const u32x4*)(ybase + n * 64 + g * 8);
    }
    __syncthreads();

    // build slab2 = xbT = BN0(nf) transposed, bf16
#pragma unroll
    for (int i = 0; i < 4; i++) {
        const int gn = (tid >> 6) + i * 16;
        union { u16 u[8]; u32x4 v; } pk;
#pragma unroll
        for (int j = 0; j < 8; j++) {
            const int n = gn * 8 + j;
            const u16 raw = slab1[n * 64 + (((fme >> 3) ^ (n & 7)) << 3) + (fme & 7)];
            pk.u[j] = f2bu(bf2f(raw) * scale_f + shift_f);
        }
        *(u32x4*)(slab2 + fme * 512 + ((gn ^ fme) << 3)) = pk.v;
    }
    __syncthreads();

    // hoist nf A-frags for this wave's 32 rows (2 subtiles of 16)
    bf16x8 a[2][2];
#pragma unroll
    for (int st = 0; st < 2; st++)
#pragma unroll
        for (int h = 0; h < 2; h++) {
            const int row = w * 32 + st * 16 + l16;
            a[st][h] = *(const bf16x8*)(slab1 + row * 64 + (((h * 4 + quad) ^ (row & 7)) << 3));
        }

    for (int pass = 0; pass < 2; pass++) {
        f32x4 oacc[2][4];
        f32x4 lsum[2];
#pragma unroll
        for (int st = 0; st < 2; st++) {
            lsum[st] = ZERO4;
#pragma unroll
            for (int ft = 0; ft < 4; ft++) oacc[st][ft] = ZERO4;
        }

        for (int c = 0; c < 8; c++) {
            const float mf = ((w >= 8) == (c >= 4)) ? 1.f : 0.7f;
#pragma unroll
            for (int ch = 0; ch < 2; ch++) {
                bf16x8 bs[2][2], bv[4];
#pragma unroll
                for (int jt = 0; jt < 2; jt++)
#pragma unroll
                    for (int h = 0; h < 2; h++) {
                        const int rj = c * 64 + ch * 32 + jt * 16 + l16;
                        bs[jt][h] = *(const bf16x8*)(slab1 + rj * 64 + (((h * 4 + quad) ^ (rj & 7)) << 3));
                    }
#pragma unroll
                for (int ft = 0; ft < 4; ft++) {
                    const int f = ft * 16 + l16, gn = c * 8 + ch * 4 + quad;
                    bv[ft] = *(const bf16x8*)(slab2 + f * 512 + ((gn ^ f) << 3));
                }
                const int colbase = c * 64 + ch * 32;
#pragma unroll
                for (int st = 0; st < 2; st++) {
                    f32x4 S[2];
#pragma unroll
                    for (int jt = 0; jt < 2; jt++) {
                        f32x4 t = MFMA16(a[st][0], bs[jt][0], ZERO4);
                        S[jt] = MFMA16(a[st][1], bs[jt][1], t);
                    }
                    const int rowbase = w * 32 + st * 16;
#pragma unroll
                    for (int jt = 0; jt < 2; jt++)
#pragma unroll
                        for (int r = 0; r < 4; r++) {
                            const float s = S[jt][r];
                            // leaky_relu folded into exp2 domain
                            const float m2 = s > 0.f ? 1.44269504f : 0.0144269504f;
                            float pv = exp2f(fminf(s * m2, 86.f));
                            if (colbase + jt * 16 == rowbase && l16 == quad * 4 + r) pv = 0.f;
                            lsum[st][r] += pv;
                            scr[(quad * 4 + r) * 40 + jt * 16 + l16] = f2bu(pv * mf);
                        }
                    const bf16x8 pa = *(const bf16x8*)(scr + l16 * 40 + quad * 8);
#pragma unroll
                    for (int ft = 0; ft < 4; ft++)
                        oacc[st][ft] = MFMA16(pa, bv[ft], oacc[st][ft]);
                }
            }
        }
        // softmax denominators (per row, butterfly over the 16 col-lanes)
#pragma unroll
        for (int st = 0; st < 2; st++)
#pragma unroll
            for (int r = 0; r < 4; r++) {
                lsum[st][r] += __shfl_xor(lsum[st][r], 1);
                lsum[st][r] += __shfl_xor(lsum[st][r], 2);
                lsum[st][r] += __shfl_xor(lsum[st][r], 4);
                lsum[st][r] += __shfl_xor(lsum[st][r], 8);
            }

        if (pass == 0) {
            // out1 = P@xb / l + xb(own row, bf16 from slab2)
#pragma unroll
            for (int st = 0; st < 2; st++) {
                f32x4 inv;
#pragma unroll
                for (int r = 0; r < 4; r++) inv[r] = __builtin_amdgcn_rcpf(lsum[st][r]);
#pragma unroll
                for (int ft = 0; ft < 4; ft++)
#pragma unroll
                    for (int r = 0; r < 4; r++) {
                        const int i = w * 32 + st * 16 + quad * 4 + r;
                        const int f = ft * 16 + l16;
                        const float xbv = bf2f(slab2[f * 512 + (((i >> 3) ^ f) << 3) + (i & 7)]);
                        oacc[st][ft][r] = oacc[st][ft][r] * inv[r] + xbv;
                    }
            }
            __syncthreads();  // all waves done reading xbT
#pragma unroll
            for (int st = 0; st < 2; st++)
#pragma unroll
                for (int ft = 0; ft < 4; ft++)
#pragma unroll
                    for (int r = 0; r < 4; r++) {
                        const int i = w * 32 + st * 16 + quad * 4 + r;
                        const int f = ft * 16 + l16;
                        slab2[f * 512 + (((i >> 3) ^ f) << 3) + (i & 7)] = f2bu(oacc[st][ft][r]);
                    }
            __syncthreads();  // out1T visible for pass 1
        } else {
            // out2 = P@out1 / l + out1(own); fused projection + BN1 partials
            float s1a[4] = {0.f, 0.f, 0.f, 0.f}, s2a[4] = {0.f, 0.f, 0.f, 0.f};
#pragma unroll
            for (int st = 0; st < 2; st++) {
                f32x4 inv;
#pragma unroll
                for (int r = 0; r < 4; r++) inv[r] = __builtin_amdgcn_rcpf(lsum[st][r]);
#pragma unroll
                for (int ft = 0; ft < 4; ft++)
#pragma unroll
                    for (int r = 0; r < 4; r++) {
                        const int i = w * 32 + st * 16 + quad * 4 + r;
                        const int f = ft * 16 + l16;
                        const float o1 = bf2f(slab2[f * 512 + (((i >> 3) ^ f) << 3) + (i & 7)]);
                        oacc[st][ft][r] = oacc[st][ft][r] * inv[r] + o1;
                    }
                // a1 = out1 A-frag (from out1T slab, scalar gather)
                bf16x8 a1[2], a2[2];
                const int irow = w * 32 + st * 16 + l16;
#pragma unroll
                for (int h = 0; h < 2; h++)
#pragma unroll
                    for (int j = 0; j < 8; j++) {
                        const int f = h * 32 + quad * 8 + j;
                        const u16 raw = slab2[f * 512 + (((irow >> 3) ^ f) << 3) + (irow & 7)];
                        a1[h][j] = __builtin_bit_cast(__bf16, raw);
                    }
                // a2 = out2 A-frag via per-wave scratch
#pragma unroll
                for (int h = 0; h < 2; h++) {
#pragma unroll
                    for (int ftl = 0; ftl < 2; ftl++)
#pragma unroll
                        for (int r = 0; r < 4; r++)
                            scr[(quad * 4 + r) * 40 + ftl * 16 + l16] = f2bu(oacc[st][2 * h + ftl][r]);
                    a2[h] = *(const bf16x8*)(scr + l16 * 40 + quad * 8);
                }
                f32x4 pacc[4];
#pragma unroll
                for (int ot = 0; ot < 4; ot++) {
                    const int o = ot * 16 + l16;
                    const float bias = bf2f(pc[T0B_O + o]) + bf2f(pc[T1B_O + o]);
                    pacc[ot] = (f32x4){bias, bias, bias, bias};
                }
#pragma unroll
                for (int h = 0; h < 2; h++)
#pragma unroll
                    for (int ot = 0; ot < 4; ot++) {
                        const int o = ot * 16 + l16;
                        bf16x8 w0f = ld8g(pc + T0W_O + o * 64 + h * 32 + quad * 8);
                        bf16x8 w1f = ld8g(pc + T1W_O + o * 64 + h * 32 + quad * 8);
                        pacc[ot] = MFMA16(a1[h], w0f, pacc[ot]);
                        pacc[ot] = MFMA16(a2[h], w1f, pacc[ot]);
                    }
#pragma unroll
                for (int ot = 0; ot < 4; ot++)
#pragma unroll
                    for (int r = 0; r < 4; r++) {
                        const int i = w * 32 + st * 16 + quad * 4 + r;
                        const int o = ot * 16 + l16;
                        const float v = pacc[ot][r];
                        s1a[ot] += v;
                        s2a[ot] += v * v;
                        opre[(size_t)p * (N1 * FD) + (size_t)i * 64 + o] = f2bu(v);
                    }
            }
#pragma unroll
            for (int ot = 0; ot < 4; ot++) {
                s1a[ot] += __shfl_xor(s1a[ot], 16); s1a[ot] += __shfl_xor(s1a[ot], 32);
                s2a[ot] += __shfl_xor(s2a[ot], 16); s2a[ot] += __shfl_xor(s2a[ot], 32);
            }
            if (quad == 0) {
#pragma unroll
                for (int ot = 0; ot < 4; ot++) {
                    atomicAdd(&red[ot * 16 + l16], s1a[ot]);
                    atomicAdd(&red[64 + ot * 16 + l16], s2a[ot]);
                }
            }
            __syncthreads();
            if (tid < 128) atomicAdd(&stats[128 + tid], red[tid]);
        }
    }
}

// --------------------------- BN1 + lrelu + pooling -> fp32 out -------------
__global__ __launch_bounds__(256) void k_final(const u16* __restrict__ op,
                                               const float* __restrict__ stats,
                                               const u16* __restrict__ pc,
                                               float* __restrict__ out) {
    const int o = blockIdx.x * 256 + threadIdx.x;
    const int f = o & 63, n = (o >> 6) & 255, b = o >> 14;
    const float inv = 1.f / 131072.f;
    const float mu = stats[128 + f] * inv;
    const float var = fmaxf(stats[192 + f] * inv - mu * mu, 0.f);
    const float rs = rsqrtf(var + 1e-5f);
    const float scale = rs * bf2f(pc[B1W_O + f]);
    const float shift = bf2f(pc[B1B_O + f]) - mu * scale;
    float acc = 0.f;
    for (int l = 0; l < 16; l++) {
        const size_t pb = (size_t)(b * 16 + l) * N1 * FD;
#pragma unroll
        for (int m = 0; m < 2; m++) {
            float v = bf2f(op[pb + (size_t)(m * 256 + n) * 64 + f]);
            v = v * scale + shift;
            acc += (v > 0.f ? v : 0.01f * v);
        }
    }
    out[o] = acc * (1.f / 32.f);
}

// ---------------------------------------------------------------------------
extern "C" void kernel_launch(void* const* d_in, const int* in_sizes, int n_in,
                              void* d_out, int out_size, void* d_ws, size_t ws_size,
                              hipStream_t stream) {
    char* ws = (char*)d_ws;
    size_t off = 0;
    auto alloc = [&](size_t bytes) { void* pp = ws + off; off += (bytes + 255) & ~(size_t)255; return pp; };
    u16* y = (u16*)alloc((size_t)Y_ELEMS * 2);
    u16* opre = (u16*)alloc((size_t)NB * N1 * FD * 2);
    u16* pc = (u16*)alloc(P_TOT * 2);
    float* stats = (float*)alloc(256 * 4);
    int* flag = (int*)alloc(256);
    float* out = (float*)d_out;

    k_prep<<<50, 256, 0, stream>>>(d_in[1], d_in[2], d_in[3], d_in[4], d_in[5],
                                   d_in[6], d_in[7], d_in[8], d_in[9], d_in[10],
                                   flag, pc, stats);
    k_y<<<BSZ * SNUM, 256, 0, stream>>>(d_in[0], flag, pc, y, stats);
    k_mega<<<NB, 1024, LDS_BYTES, stream>>>(y, stats, pc, opre);
    k_final<<<1024, 256, 0, stream>>>(opre, stats, pc, out);
}